// Round 11
// baseline (2574.546 us; speedup 1.0000x reference)
//
#include <hip/hip_runtime.h>
#include <hip/hip_fp16.h>
#include <math.h>

#define B_ 64
#define T_ 512

typedef _Float16 h2_t __attribute__((ext_vector_type(2)));

__device__ __forceinline__ float fdot2u(unsigned int a, unsigned int b, float c) {
#if __has_builtin(__builtin_amdgcn_fdot2)
    return __builtin_amdgcn_fdot2(__builtin_bit_cast(h2_t, a),
                                  __builtin_bit_cast(h2_t, b), c, false);
#else
    const __half2 ah = __builtin_bit_cast(__half2, a);
    const __half2 bh = __builtin_bit_cast(__half2, b);
    const float2 af = __half22float2(ah), bf = __half22float2(bh);
    return c + af.x * bf.x + af.y * bf.y;
#endif
}
__device__ __forceinline__ unsigned int pack_h2(float x, float y) {
    const __half2 h = __float22half2_rn(make_float2(x, y));
    return __builtin_bit_cast(unsigned int, h);
}
__device__ __forceinline__ float ubits(unsigned int a) { return __builtin_bit_cast(float, a); }
__device__ __forceinline__ unsigned short f2h_bits(float x) {
    return __builtin_bit_cast(unsigned short, (_Float16)x);
}

__device__ __forceinline__ float fsig(float z) { return 1.f / (1.f + __expf(-z)); }
__device__ __forceinline__ float ftanh(float z) {
    const float e = __expf(2.f * z);
    return 1.f - 2.f / (e + 1.f);
}

// LDS-only barrier: lgkmcnt(0) + s_barrier, no vmcnt drain (v12-proven).
__device__ __forceinline__ void bar_lds() {
    asm volatile("s_waitcnt lgkmcnt(0)" ::: "memory");
    __builtin_amdgcn_s_barrier();
    asm volatile("" ::: "memory");
}

// Pull a wave-uniform word out of a distributed-load VGPR into an SGPR.
__device__ __forceinline__ unsigned int rl(unsigned int v, int lane) {
    return (unsigned int)__builtin_amdgcn_readlane((int)v, lane);
}

// ---------------------------------------------------------------------------
// GEMM v2 (unchanged): C[M,N] = (A*mask)@W + bias, packed-fp16 dot2.
// ---------------------------------------------------------------------------
__global__ __launch_bounds__(256) void gemm_mask_f16(
    const float* __restrict__ A, const float* __restrict__ W,
    const float* __restrict__ bias, const float* __restrict__ mask,
    float* __restrict__ C, int M, int N, int K)
{
    const int TM = 64, TN = 64, TK = 32, KP = 16;
    __shared__ __align__(16) unsigned int As2[KP][68];
    __shared__ __align__(16) unsigned int Bs2[KP][68];

    const int tid = threadIdx.x;
    const int bn = blockIdx.x;
    const int bm = blockIdx.y;
    const int row0 = bm * TM;
    const int b = row0 / T_;

    const int ty = tid >> 4;
    const int tx = tid & 15;
    const int m0 = ty * 4;
    const int n0 = tx * 4;

    float acc[4][4];
#pragma unroll
    for (int i = 0; i < 4; i++)
#pragma unroll
        for (int j = 0; j < 4; j++) acc[i][j] = 0.f;

    for (int kk = 0; kk < K; kk += TK) {
        {
            const int m = tid >> 2;
            const int kq = (tid & 3) * 8;
            const float4 mv0 = *(const float4*)(mask + (size_t)b * K + kk + kq);
            const float4 mv1 = *(const float4*)(mask + (size_t)b * K + kk + kq + 4);
            const float4 a0 = *(const float4*)(A + (size_t)(row0 + m) * K + kk + kq);
            const float4 a1 = *(const float4*)(A + (size_t)(row0 + m) * K + kk + kq + 4);
            As2[kq / 2 + 0][m] = pack_h2(a0.x * mv0.x, a0.y * mv0.y);
            As2[kq / 2 + 1][m] = pack_h2(a0.z * mv0.z, a0.w * mv0.w);
            As2[kq / 2 + 2][m] = pack_h2(a1.x * mv1.x, a1.y * mv1.y);
            As2[kq / 2 + 3][m] = pack_h2(a1.z * mv1.z, a1.w * mv1.w);
        }
        {
            const int kp = tid >> 4;
            const int nq = (tid & 15) * 4;
            const float4 w0 = *(const float4*)(W + (size_t)(kk + 2 * kp) * N + bn * TN + nq);
            const float4 w1 = *(const float4*)(W + (size_t)(kk + 2 * kp + 1) * N + bn * TN + nq);
            uint4 pv;
            pv.x = pack_h2(w0.x, w1.x);
            pv.y = pack_h2(w0.y, w1.y);
            pv.z = pack_h2(w0.z, w1.z);
            pv.w = pack_h2(w0.w, w1.w);
            *(uint4*)&Bs2[kp][nq] = pv;
        }
        __syncthreads();

#pragma unroll
        for (int kp = 0; kp < KP; kp++) {
            const uint4 a4 = *(const uint4*)&As2[kp][m0];
            const uint4 b4 = *(const uint4*)&Bs2[kp][n0];
            acc[0][0] = fdot2u(a4.x, b4.x, acc[0][0]); acc[0][1] = fdot2u(a4.x, b4.y, acc[0][1]);
            acc[0][2] = fdot2u(a4.x, b4.z, acc[0][2]); acc[0][3] = fdot2u(a4.x, b4.w, acc[0][3]);
            acc[1][0] = fdot2u(a4.y, b4.x, acc[1][0]); acc[1][1] = fdot2u(a4.y, b4.y, acc[1][1]);
            acc[1][2] = fdot2u(a4.y, b4.z, acc[1][2]); acc[1][3] = fdot2u(a4.y, b4.w, acc[1][3]);
            acc[2][0] = fdot2u(a4.z, b4.x, acc[2][0]); acc[2][1] = fdot2u(a4.z, b4.y, acc[2][1]);
            acc[2][2] = fdot2u(a4.z, b4.z, acc[2][2]); acc[2][3] = fdot2u(a4.z, b4.w, acc[2][3]);
            acc[3][0] = fdot2u(a4.w, b4.x, acc[3][0]); acc[3][1] = fdot2u(a4.w, b4.y, acc[3][1]);
            acc[3][2] = fdot2u(a4.w, b4.z, acc[3][2]); acc[3][3] = fdot2u(a4.w, b4.w, acc[3][3]);
        }
        __syncthreads();
    }

    const float4 bv = *(const float4*)(bias + bn * TN + n0);
#pragma unroll
    for (int i = 0; i < 4; i++) {
        float4 v;
        v.x = acc[i][0] + bv.x;
        v.y = acc[i][1] + bv.y;
        v.z = acc[i][2] + bv.z;
        v.w = acc[i][3] + bv.w;
        *(float4*)&C[(size_t)(row0 + m0 + i) * N + bn * TN + n0] = v;
    }
}

// ---------------------------------------------------------------------------
// LSTM v20-half: v19 (2-way split, proven correct r10) with the wave-uniform
// hW reads replaced by ONE distributed ds_read_b128 + readlane->SGPR.
// r10 post-mortem: v19's regression (697->795) was the doubled hW broadcast
// (8 b128/thread/step, 128/CU on the SHARED per-CU LDS pipe ~1100-1500cy).
// New scheme: lane l loads hW[wbase+4*(l&7)..+4] (8 distinct addrs, conflict
// free, ONE b128 per wave), then each word reaches the dot as an SGPR via
// readlane(hv.comp, const_lane) -- v_dot2 takes 1 SGPR operand. LDS issue
// for hW: 128 -> 16 instr/CU/step. Everything else identical to v19.
// ---------------------------------------------------------------------------
__global__ __launch_bounds__(1024, 4) void lstm_half_v20(
    const float* __restrict__ xz,       // [B, T, 1024]
    const float* __restrict__ U,        // [256, 1024]
    float* __restrict__ hout,           // [B, T, 256]
    unsigned int* __restrict__ hbuf)    // [2][B_*256] tagged words
{
    constexpr int HN = 256;
    constexpr int GATES = 1024;
    constexpr int COLS = 512;           // 4 gates x 128 owned units
    constexpr int CP = COLS / 2;        // 256 col-pairs
    constexpr int NKG = 1024 / CP;      // 4 k-groups
    constexpr int KH = HN / NKG;        // 64 k per group
    constexpr int WPT = KH / 2;         // 32 f16-pair words per thread
    constexpr int HOWN = 128;           // units owned by this block
    constexpr int KWORDS = HN / 2;      // 128 hW words (f16 pairs over k)
    constexpr int COLSP = COLS + 2;     // 514

    __shared__ __align__(16) unsigned int hW[KWORDS];
    __shared__ __align__(16) float zpS[NKG * COLSP];

    const int tid = threadIdx.x;
    const int s = blockIdx.x >> 6;      // half 0/1
    const int b = blockIdx.x & 63;      // batch element (sibling 64 apart -> same XCD)

    const int cp = tid % CP;
    const int kq = tid / CP;            // wave-uniform (CP = 256)
    const int c0 = 2 * cp;              // local col (gate*128 + unit_local)
    const int group = c0 / HOWN;        // gate 0..3
    const int gcol = group * HN + s * HOWN + (c0 % HOWN);
    const int wbase = kq * WPT;
    const int lslot = tid & 7;          // distributed-load slot within wave

    // ---- one-time: U slice into registers (f16-packed over k), then PIN ----
    uint2 ur[WPT];
#pragma unroll
    for (int j = 0; j < WPT; ++j) {
        const int w = wbase + j;
        const float2 r0 = *(const float2*)(U + (size_t)(2 * w) * GATES + gcol);
        const float2 r1 = *(const float2*)(U + (size_t)(2 * w + 1) * GATES + gcol);
        ur[j].x = pack_h2(r0.x, r1.x);
        ur[j].y = pack_h2(r0.y, r1.y);
    }
#pragma unroll
    for (int j = 0; j < WPT; ++j)
        asm volatile("" : "+v"(ur[j].x), "+v"(ur[j].y));

    if (tid < KWORDS) hW[tid] = 0u;     // h_0 = 0
    float cst = 0.f;

    const float* xzcell = xz + (size_t)b * T_ * GATES + s * HOWN + tid;
    float z4a[4] = {0.f, 0.f, 0.f, 0.f};
    float z4b[4] = {0.f, 0.f, 0.f, 0.f};
    if (tid < HOWN) {
#pragma unroll
        for (int g = 0; g < 4; ++g) z4a[g] = xzcell[g * HN];            // t=0
#pragma unroll
        for (int g = 0; g < 4; ++g) z4b[g] = xzcell[GATES + g * HN];    // t=1
    }
    __syncthreads();   // one-time init barrier

#define V20_STEP(TT, Z)                                                        \
    {                                                                          \
        /* one distributed b128: lane l holds words wbase+4*(l&7)..+4 */       \
        const uint4 hv = *(const uint4*)&hW[wbase + 4 * lslot];                \
        float acc0 = 0.f, acc1 = 0.f;                                          \
        _Pragma("unroll")                                                      \
        for (int j = 0; j < WPT; j += 4) {                                     \
            const int ln = j >> 2;                                             \
            const unsigned int h0 = rl(hv.x, ln);                              \
            const unsigned int h1 = rl(hv.y, ln);                              \
            const unsigned int h2 = rl(hv.z, ln);                              \
            const unsigned int h3 = rl(hv.w, ln);                              \
            acc0 = fdot2u(ur[j + 0].x, h0, acc0); acc1 = fdot2u(ur[j + 0].y, h0, acc1); \
            acc0 = fdot2u(ur[j + 1].x, h1, acc0); acc1 = fdot2u(ur[j + 1].y, h1, acc1); \
            acc0 = fdot2u(ur[j + 2].x, h2, acc0); acc1 = fdot2u(ur[j + 2].y, h2, acc1); \
            acc0 = fdot2u(ur[j + 3].x, h3, acc0); acc1 = fdot2u(ur[j + 3].y, h3, acc1); \
        }                                                                      \
        *(float2*)&zpS[kq * COLSP + c0] = make_float2(acc0, acc1);             \
        bar_lds();                                                             \
        const unsigned int tag = (unsigned int)((TT) + 1);                     \
        unsigned int* hslot = hbuf + (size_t)((TT) & 1) * B_ * HN + b * HN;    \
        if (tid < HOWN) {                                                      \
            float zg[4];                                                       \
            _Pragma("unroll")                                                  \
            for (int g = 0; g < 4; ++g) {                                      \
                float zs = Z[g];                                               \
                _Pragma("unroll")                                              \
                for (int r = 0; r < NKG; ++r) zs += zpS[r * COLSP + g * HOWN + tid]; \
                zg[g] = zs;                                                    \
            }                                                                  \
            if ((TT) + 2 < T_) {                                               \
                _Pragma("unroll")                                              \
                for (int g = 0; g < 4; ++g)                                    \
                    Z[g] = xzcell[(size_t)((TT) + 2) * GATES + g * HN];        \
            }                                                                  \
            const float ig = fsig(zg[0]);                                      \
            const float fg = fsig(zg[1]);                                      \
            const float gg = ftanh(zg[2]);                                     \
            const float og = fsig(zg[3]);                                      \
            cst = fg * cst + ig * gg;                                          \
            const float hnew = og * ftanh(cst);                                \
            hout[((size_t)b * T_ + (TT)) * HN + s * HOWN + tid] = hnew;        \
            if ((TT) < T_ - 1) {                                               \
                const unsigned short h16 = f2h_bits(hnew);                     \
                __hip_atomic_store(&hslot[s * HOWN + tid],                     \
                                   (tag << 16) | (unsigned int)h16,            \
                                   __ATOMIC_RELAXED, __HIP_MEMORY_SCOPE_AGENT);\
                reinterpret_cast<unsigned short*>(hW)[s * HOWN + tid] = h16;   \
            }                                                                  \
        } else if (tid >= 128 && tid < 192 && (TT) < T_ - 1) {                 \
            const int p = (1 - s) * 64 + (tid - 128);  /* remote hW word */    \
            const unsigned long long* hq = (const unsigned long long*)hslot;   \
            unsigned long long v = __hip_atomic_load(&hq[p],                   \
                __ATOMIC_RELAXED, __HIP_MEMORY_SCOPE_AGENT);                   \
            while (((v >> 16) & 0xffffu) != tag || (v >> 48) != tag)           \
                v = __hip_atomic_load(&hq[p],                                  \
                    __ATOMIC_RELAXED, __HIP_MEMORY_SCOPE_AGENT);               \
            hW[p] = (unsigned int)(v & 0xffffu) |                              \
                    ((unsigned int)((v >> 32) & 0xffffu) << 16);               \
        }                                                                      \
        bar_lds();                                                             \
    }

#pragma unroll 1
    for (int t = 0; t < T_; t += 2) {
        V20_STEP(t, z4a)
        V20_STEP(t + 1, z4b)
    }
#undef V20_STEP
}

// ---------------------------------------------------------------------------
// LSTM v20-full: layer 2 (HN=128), one block per batch, NO exchange (r9:
// 705->~470us), now with the same distributed-b128 + readlane hW path
// (128 -> 16 LDS instr/CU/step; this kernel was the most hW-LDS-bound).
// ---------------------------------------------------------------------------
__global__ __launch_bounds__(1024, 4) void lstm_full_v20(
    const float* __restrict__ xz,       // [B, T, 512]
    const float* __restrict__ U,        // [128, 512]
    float* __restrict__ out_last)       // [B, 128]
{
    constexpr int HN = 128;
    constexpr int GATES = 512;
    constexpr int COLS = 512;
    constexpr int CP = COLS / 2;        // 256
    constexpr int NKG = 1024 / CP;      // 4
    constexpr int KH = HN / NKG;        // 32
    constexpr int WPT = KH;             // 32 f32-pair entries
    constexpr int KWORDS = HN;          // 128 f32 h words
    constexpr int COLSP = COLS + 2;

    __shared__ __align__(16) unsigned int hW[KWORDS];
    __shared__ __align__(16) float zpS[NKG * COLSP];

    const int tid = threadIdx.x;
    const int b = blockIdx.x;

    const int cp = tid % CP;
    const int kq = tid / CP;            // wave-uniform
    const int c0 = 2 * cp;
    const int wbase = kq * WPT;
    const int lslot = tid & 7;

    uint2 ur[WPT];
#pragma unroll
    for (int j = 0; j < WPT; ++j) {
        const int w = wbase + j;
        const float2 r0 = *(const float2*)(U + (size_t)w * GATES + c0);
        ur[j].x = __builtin_bit_cast(unsigned int, r0.x);
        ur[j].y = __builtin_bit_cast(unsigned int, r0.y);
    }
#pragma unroll
    for (int j = 0; j < WPT; ++j)
        asm volatile("" : "+v"(ur[j].x), "+v"(ur[j].y));

    if (tid < KWORDS) hW[tid] = 0u;
    float cst = 0.f;

    const float* xzcell = xz + (size_t)b * T_ * GATES + tid;
    float z4a[4] = {0.f, 0.f, 0.f, 0.f};
    float z4b[4] = {0.f, 0.f, 0.f, 0.f};
    if (tid < HN) {
#pragma unroll
        for (int g = 0; g < 4; ++g) z4a[g] = xzcell[g * HN];            // t=0
#pragma unroll
        for (int g = 0; g < 4; ++g) z4b[g] = xzcell[GATES + g * HN];    // t=1
    }
    __syncthreads();

#define V20F_STEP(TT, Z)                                                       \
    {                                                                          \
        const uint4 hv = *(const uint4*)&hW[wbase + 4 * lslot];                \
        float acc0 = 0.f, acc1 = 0.f;                                          \
        _Pragma("unroll")                                                      \
        for (int j = 0; j < WPT; j += 4) {                                     \
            const int ln = j >> 2;                                             \
            const float h0 = ubits(rl(hv.x, ln));                              \
            const float h1 = ubits(rl(hv.y, ln));                              \
            const float h2 = ubits(rl(hv.z, ln));                              \
            const float h3 = ubits(rl(hv.w, ln));                              \
            acc0 += ubits(ur[j + 0].x) * h0; acc1 += ubits(ur[j + 0].y) * h0;  \
            acc0 += ubits(ur[j + 1].x) * h1; acc1 += ubits(ur[j + 1].y) * h1;  \
            acc0 += ubits(ur[j + 2].x) * h2; acc1 += ubits(ur[j + 2].y) * h2;  \
            acc0 += ubits(ur[j + 3].x) * h3; acc1 += ubits(ur[j + 3].y) * h3;  \
        }                                                                      \
        *(float2*)&zpS[kq * COLSP + c0] = make_float2(acc0, acc1);             \
        bar_lds();                                                             \
        if (tid < HN) {                                                        \
            float zg[4];                                                       \
            _Pragma("unroll")                                                  \
            for (int g = 0; g < 4; ++g) {                                      \
                float zs = Z[g];                                               \
                _Pragma("unroll")                                              \
                for (int r = 0; r < NKG; ++r) zs += zpS[r * COLSP + g * HN + tid]; \
                zg[g] = zs;                                                    \
            }                                                                  \
            if ((TT) + 2 < T_) {                                               \
                _Pragma("unroll")                                              \
                for (int g = 0; g < 4; ++g)                                    \
                    Z[g] = xzcell[(size_t)((TT) + 2) * GATES + g * HN];        \
            }                                                                  \
            const float ig = fsig(zg[0]);                                      \
            const float fg = fsig(zg[1]);                                      \
            const float gg = ftanh(zg[2]);                                     \
            const float og = fsig(zg[3]);                                      \
            cst = fg * cst + ig * gg;                                          \
            const float hnew = og * ftanh(cst);                                \
            if ((TT) == T_ - 1) {                                              \
                out_last[(size_t)b * HN + tid] = hnew;                         \
            } else {                                                           \
                hW[tid] = __builtin_bit_cast(unsigned int, hnew);              \
            }                                                                  \
        }                                                                      \
        bar_lds();                                                             \
    }

#pragma unroll 1
    for (int t = 0; t < T_; t += 2) {
        V20F_STEP(t, z4a)
        V20F_STEP(t + 1, z4b)
    }
#undef V20F_STEP
}

// ---------------------------------------------------------------------------
// Launch
// ---------------------------------------------------------------------------
extern "C" void kernel_launch(void* const* d_in, const int* in_sizes, int n_in,
                              void* d_out, int out_size, void* d_ws, size_t ws_size,
                              hipStream_t stream)
{
    const float* x  = (const float*)d_in[0];
    const float* W0 = (const float*)d_in[1];
    const float* U0 = (const float*)d_in[2];
    const float* b0 = (const float*)d_in[3];
    const float* W1 = (const float*)d_in[4];
    const float* U1 = (const float*)d_in[5];
    const float* b1 = (const float*)d_in[6];
    const float* W2 = (const float*)d_in[7];
    const float* U2 = (const float*)d_in[8];
    const float* b2 = (const float*)d_in[9];
    const float* m0 = (const float*)d_in[10];
    const float* m1 = (const float*)d_in[11];
    const float* m2 = (const float*)d_in[12];
    float* out = (float*)d_out;

    // workspace layout:
    //   xz    : 134217728 B   (64*512*1024 floats, reused by all 3 layers)
    //   h0    :  33554432 B
    //   h1    :  33554432 B
    //   hbuf  : 2 regions x 131072 B (2 x 64 x 256 tagged words per layer)
    char* ws = (char*)d_ws;
    float* xz = (float*)ws;
    float* h0 = (float*)(ws + 134217728);
    float* h1 = (float*)(ws + 134217728 + 33554432);
    unsigned int* hb0 = (unsigned int*)(ws + 134217728 + 2 * 33554432);
    unsigned int* hb1 = hb0 + 2 * B_ * 256;

    const int M = B_ * T_;  // 32768

    // Layer 0
    gemm_mask_f16<<<dim3(1024 / 64, M / 64), 256, 0, stream>>>(x, W0, b0, m0, xz, M, 1024, 128);
    lstm_half_v20<<<128, 1024, 0, stream>>>(xz, U0, h0, hb0);

    // Layer 1
    gemm_mask_f16<<<dim3(1024 / 64, M / 64), 256, 0, stream>>>(h0, W1, b1, m1, xz, M, 1024, 256);
    lstm_half_v20<<<128, 1024, 0, stream>>>(xz, U1, h1, hb1);

    // Layer 2 (H=128): one block per batch, NO exchange, readlane dot
    gemm_mask_f16<<<dim3(512 / 64, M / 64), 256, 0, stream>>>(h1, W2, b2, m2, xz, M, 512, 256);
    lstm_full_v20<<<64, 1024, 0, stream>>>(xz, U2, out);
}

// Round 12
// 2116.413 us; speedup vs baseline: 1.2165x; 1.2165x over previous
//
#include <hip/hip_runtime.h>
#include <hip/hip_fp16.h>
#include <math.h>

#define B_ 64
#define T_ 512

typedef _Float16 h2_t __attribute__((ext_vector_type(2)));

__device__ __forceinline__ float fdot2u(unsigned int a, unsigned int b, float c) {
#if __has_builtin(__builtin_amdgcn_fdot2)
    return __builtin_amdgcn_fdot2(__builtin_bit_cast(h2_t, a),
                                  __builtin_bit_cast(h2_t, b), c, false);
#else
    const __half2 ah = __builtin_bit_cast(__half2, a);
    const __half2 bh = __builtin_bit_cast(__half2, b);
    const float2 af = __half22float2(ah), bf = __half22float2(bh);
    return c + af.x * bf.x + af.y * bf.y;
#endif
}
__device__ __forceinline__ unsigned int pack_h2(float x, float y) {
    const __half2 h = __float22half2_rn(make_float2(x, y));
    return __builtin_bit_cast(unsigned int, h);
}
__device__ __forceinline__ float ubits(unsigned int a) { return __builtin_bit_cast(float, a); }
__device__ __forceinline__ unsigned short f2h_bits(float x) {
    return __builtin_bit_cast(unsigned short, (_Float16)x);
}
__device__ __forceinline__ float h2f_bits(unsigned int bits) {
    return (float)__builtin_bit_cast(_Float16, (unsigned short)(bits & 0xffffu));
}

__device__ __forceinline__ float fsig(float z) { return 1.f / (1.f + __expf(-z)); }
__device__ __forceinline__ float ftanh(float z) {
    const float e = __expf(2.f * z);
    return 1.f - 2.f / (e + 1.f);
}

// LDS-only barrier: lgkmcnt(0) + s_barrier, no vmcnt drain (v12-proven).
__device__ __forceinline__ void bar_lds() {
    asm volatile("s_waitcnt lgkmcnt(0)" ::: "memory");
    __builtin_amdgcn_s_barrier();
    asm volatile("" ::: "memory");
}

// ---------------------------------------------------------------------------
// GEMM v2: C[M,N] = (A[M,K]*mask)@W[K,N] + bias, packed-fp16 dot2 inner loop.
// 64x64 tile, TK=32 (16 k-pairs), 256 threads, 4x4 microtile. (unchanged)
// ---------------------------------------------------------------------------
__global__ __launch_bounds__(256) void gemm_mask_f16(
    const float* __restrict__ A, const float* __restrict__ W,
    const float* __restrict__ bias, const float* __restrict__ mask,
    float* __restrict__ C, int M, int N, int K)
{
    const int TM = 64, TN = 64, TK = 32, KP = 16;
    __shared__ __align__(16) unsigned int As2[KP][68];
    __shared__ __align__(16) unsigned int Bs2[KP][68];

    const int tid = threadIdx.x;
    const int bn = blockIdx.x;
    const int bm = blockIdx.y;
    const int row0 = bm * TM;
    const int b = row0 / T_;

    const int ty = tid >> 4;
    const int tx = tid & 15;
    const int m0 = ty * 4;
    const int n0 = tx * 4;

    float acc[4][4];
#pragma unroll
    for (int i = 0; i < 4; i++)
#pragma unroll
        for (int j = 0; j < 4; j++) acc[i][j] = 0.f;

    for (int kk = 0; kk < K; kk += TK) {
        {
            const int m = tid >> 2;
            const int kq = (tid & 3) * 8;
            const float4 mv0 = *(const float4*)(mask + (size_t)b * K + kk + kq);
            const float4 mv1 = *(const float4*)(mask + (size_t)b * K + kk + kq + 4);
            const float4 a0 = *(const float4*)(A + (size_t)(row0 + m) * K + kk + kq);
            const float4 a1 = *(const float4*)(A + (size_t)(row0 + m) * K + kk + kq + 4);
            As2[kq / 2 + 0][m] = pack_h2(a0.x * mv0.x, a0.y * mv0.y);
            As2[kq / 2 + 1][m] = pack_h2(a0.z * mv0.z, a0.w * mv0.w);
            As2[kq / 2 + 2][m] = pack_h2(a1.x * mv1.x, a1.y * mv1.y);
            As2[kq / 2 + 3][m] = pack_h2(a1.z * mv1.z, a1.w * mv1.w);
        }
        {
            const int kp = tid >> 4;
            const int nq = (tid & 15) * 4;
            const float4 w0 = *(const float4*)(W + (size_t)(kk + 2 * kp) * N + bn * TN + nq);
            const float4 w1 = *(const float4*)(W + (size_t)(kk + 2 * kp + 1) * N + bn * TN + nq);
            uint4 pv;
            pv.x = pack_h2(w0.x, w1.x);
            pv.y = pack_h2(w0.y, w1.y);
            pv.z = pack_h2(w0.z, w1.z);
            pv.w = pack_h2(w0.w, w1.w);
            *(uint4*)&Bs2[kp][nq] = pv;
        }
        __syncthreads();

#pragma unroll
        for (int kp = 0; kp < KP; kp++) {
            const uint4 a4 = *(const uint4*)&As2[kp][m0];
            const uint4 b4 = *(const uint4*)&Bs2[kp][n0];
            acc[0][0] = fdot2u(a4.x, b4.x, acc[0][0]); acc[0][1] = fdot2u(a4.x, b4.y, acc[0][1]);
            acc[0][2] = fdot2u(a4.x, b4.z, acc[0][2]); acc[0][3] = fdot2u(a4.x, b4.w, acc[0][3]);
            acc[1][0] = fdot2u(a4.y, b4.x, acc[1][0]); acc[1][1] = fdot2u(a4.y, b4.y, acc[1][1]);
            acc[1][2] = fdot2u(a4.y, b4.z, acc[1][2]); acc[1][3] = fdot2u(a4.y, b4.w, acc[1][3]);
            acc[2][0] = fdot2u(a4.z, b4.x, acc[2][0]); acc[2][1] = fdot2u(a4.z, b4.y, acc[2][1]);
            acc[2][2] = fdot2u(a4.z, b4.z, acc[2][2]); acc[2][3] = fdot2u(a4.z, b4.w, acc[2][3]);
            acc[3][0] = fdot2u(a4.w, b4.x, acc[3][0]); acc[3][1] = fdot2u(a4.w, b4.y, acc[3][1]);
            acc[3][2] = fdot2u(a4.w, b4.z, acc[3][2]); acc[3][3] = fdot2u(a4.w, b4.w, acc[3][3]);
        }
        __syncthreads();
    }

    const float4 bv = *(const float4*)(bias + bn * TN + n0);
#pragma unroll
    for (int i = 0; i < 4; i++) {
        float4 v;
        v.x = acc[i][0] + bv.x;
        v.y = acc[i][1] + bv.y;
        v.z = acc[i][2] + bv.z;
        v.w = acc[i][3] + bv.w;
        *(float4*)&C[(size_t)(row0 + m0 + i) * N + bn * TN + n0] = v;
    }
}

// ---------------------------------------------------------------------------
// LSTM recurrence v16 (r9-verified best: ~697us/dispatch): v13 2-phase
// structure + pinned-register U + conflict-free zpart. 4-way split, tagged
// L2 exchange. Lessons encoded: (r8) INLINE phase bodies only -- lambda
// variants demote ur[] to scratch; (r10) 2-way split regresses (longer
// serial dot outweighs smaller exchange); (r11) readlane hW path regresses
// (broadcast b128 reads were not the bottleneck).
// ---------------------------------------------------------------------------
template <int HN, bool F16>
__global__ __launch_bounds__(1024, 4) void lstm_rec_v16(
    const float* __restrict__ xz,       // [B, T, 4*HN]
    const float* __restrict__ U,        // [HN, 4*HN]
    float* __restrict__ hout,           // [B, T, HN] or nullptr
    float* __restrict__ out_last,       // [B, HN] or nullptr
    unsigned int* __restrict__ hbuf)    // [2][B_*HN] tagged words
{
    constexpr int GATES = 4 * HN;
    constexpr int COLS = HN;
    constexpr int CP = COLS / 2;
    constexpr int NKG = 1024 / CP;
    constexpr int KH = HN / NKG;
    constexpr int HB = HN / 4;
    constexpr int KWORDS = F16 ? HN / 2 : HN;
    constexpr int WPT = F16 ? KH / 2 : KH;
    constexpr int COLSP = COLS + 2;
    constexpr int NR = 3 * HB / 2;

    __shared__ __align__(16) unsigned int hW[KWORDS];
    __shared__ __align__(16) float zpS[NKG * COLSP];

    const int tid = threadIdx.x;
    const int q = blockIdx.x >> 6;      // quarter 0..3
    const int b = blockIdx.x & 63;      // batch element (siblings 64 apart -> same XCD)

    const int cp = tid % CP;
    const int kq = tid / CP;            // wave-uniform (CP % 64 == 0)
    const int c0 = 2 * cp;
    const int group = c0 / HB;
    const int gcol = group * HN + q * HB + (c0 % HB);
    const int wbase = kq * WPT;

    // ---- one-time: load this thread's U slice into REGISTERS, then PIN ----
    uint2 ur[WPT];
#pragma unroll
    for (int j = 0; j < WPT; ++j) {
        const int w = wbase + j;
        if constexpr (F16) {
            const float2 r0 = *(const float2*)(U + (size_t)(2 * w) * GATES + gcol);
            const float2 r1 = *(const float2*)(U + (size_t)(2 * w + 1) * GATES + gcol);
            ur[j].x = pack_h2(r0.x, r1.x);
            ur[j].y = pack_h2(r0.y, r1.y);
        } else {
            const float2 r0 = *(const float2*)(U + (size_t)w * GATES + gcol);
            ur[j].x = __builtin_bit_cast(unsigned int, r0.x);
            ur[j].y = __builtin_bit_cast(unsigned int, r0.y);
        }
    }
#pragma unroll
    for (int j = 0; j < WPT; ++j)
        asm volatile("" : "+v"(ur[j].x), "+v"(ur[j].y));

    if (tid < KWORDS) hW[tid] = 0u;     // h_0 = 0
    float cst = 0.f;

    const float* xzcell = xz + (size_t)b * T_ * GATES + q * HB + tid;
    float z4[4] = {0.f, 0.f, 0.f, 0.f};
    if (tid < HB) {
#pragma unroll
        for (int g = 0; g < 4; ++g) z4[g] = xzcell[(size_t)g * HN];   // t=0
    }
    __syncthreads();   // one-time init barrier

#pragma unroll 1
    for (int t = 0; t < T_; ++t) {
        // ---- phase A: dot (U in regs, h from LDS) ----
        float acc0 = 0.f, acc1 = 0.f;
#pragma unroll
        for (int j = 0; j < WPT; j += 4) {
            const int w = wbase + j;
            const uint4 hw4 = *(const uint4*)&hW[w];    // wave-uniform broadcast
            if constexpr (F16) {
                acc0 = fdot2u(ur[j + 0].x, hw4.x, acc0); acc1 = fdot2u(ur[j + 0].y, hw4.x, acc1);
                acc0 = fdot2u(ur[j + 1].x, hw4.y, acc0); acc1 = fdot2u(ur[j + 1].y, hw4.y, acc1);
                acc0 = fdot2u(ur[j + 2].x, hw4.z, acc0); acc1 = fdot2u(ur[j + 2].y, hw4.z, acc1);
                acc0 = fdot2u(ur[j + 3].x, hw4.w, acc0); acc1 = fdot2u(ur[j + 3].y, hw4.w, acc1);
            } else {
                acc0 += ubits(ur[j + 0].x) * ubits(hw4.x); acc1 += ubits(ur[j + 0].y) * ubits(hw4.x);
                acc0 += ubits(ur[j + 1].x) * ubits(hw4.y); acc1 += ubits(ur[j + 1].y) * ubits(hw4.y);
                acc0 += ubits(ur[j + 2].x) * ubits(hw4.z); acc1 += ubits(ur[j + 2].y) * ubits(hw4.z);
                acc0 += ubits(ur[j + 3].x) * ubits(hw4.w); acc1 += ubits(ur[j + 3].y) * ubits(hw4.w);
            }
        }
        *(float2*)&zpS[kq * COLSP + c0] = make_float2(acc0, acc1);
        bar_lds();          // bar1

        const unsigned int tag = (unsigned int)(t + 1);
        unsigned int* hslot = hbuf + (size_t)(t & 1) * B_ * HN + b * HN;

        if (tid < HB) {
            float zg[4];
#pragma unroll
            for (int g = 0; g < 4; ++g) {
                float zs = z4[g];
#pragma unroll
                for (int r = 0; r < NKG; ++r) zs += zpS[r * COLSP + g * HB + tid];
                zg[g] = zs;
            }
            if (t + 1 < T_) {
#pragma unroll
                for (int g = 0; g < 4; ++g)
                    z4[g] = xzcell[(size_t)(t + 1) * GATES + (size_t)g * HN];
            }
            const float ig = fsig(zg[0]);
            const float fg = fsig(zg[1]);
            const float gg = ftanh(zg[2]);
            const float og = fsig(zg[3]);
            cst = fg * cst + ig * gg;
            const float hnew = og * ftanh(cst);

            if (hout) hout[((size_t)b * T_ + t) * HN + q * HB + tid] = hnew;
            if (t == T_ - 1) {
                if (out_last) out_last[(size_t)b * HN + q * HB + tid] = hnew;
            } else {
                const unsigned short h16 = f2h_bits(hnew);
                __hip_atomic_store(&hslot[q * HB + tid],
                                   ((unsigned int)tag << 16) | (unsigned int)h16,
                                   __ATOMIC_RELAXED, __HIP_MEMORY_SCOPE_AGENT);
                if constexpr (F16) {
                    reinterpret_cast<unsigned short*>(hW)[q * HB + tid] = h16;
                } else {
                    hW[q * HB + tid] = __builtin_bit_cast(unsigned int, hnew);
                }
            }
        } else if (tid >= 64 && tid < 64 + NR && t < T_ - 1) {
            const int idx = tid - 64;
            const int qp0 = q * (HB / 2);
            const int p = idx + (idx >= qp0 ? (HB / 2) : 0);   // remote pair index
            const unsigned long long* hq = (const unsigned long long*)hslot;
            unsigned long long v = __hip_atomic_load(&hq[p],
                __ATOMIC_RELAXED, __HIP_MEMORY_SCOPE_AGENT);
            while (((v >> 16) & 0xffffu) != tag || (v >> 48) != tag)
                v = __hip_atomic_load(&hq[p],
                    __ATOMIC_RELAXED, __HIP_MEMORY_SCOPE_AGENT);
            if constexpr (F16) {
                hW[p] = (unsigned int)(v & 0xffffu) |
                        ((unsigned int)((v >> 32) & 0xffffu) << 16);
            } else {
                hW[2 * p + 0] = __builtin_bit_cast(unsigned int, h2f_bits((unsigned int)v));
                hW[2 * p + 1] = __builtin_bit_cast(unsigned int, h2f_bits((unsigned int)(v >> 32)));
            }
        }
        bar_lds();          // bar2
    }
}

// ---------------------------------------------------------------------------
// LSTM recurrence v18-full (r9-verified: ~470us): ONE block per batch
// element, NO exchange, h entirely in LDS. Step = dot -> bar -> cell -> bar.
// (r10's 2-step-ahead prefetch variant was neutral-to-worse; keep 1-step.)
// ---------------------------------------------------------------------------
__global__ __launch_bounds__(1024, 4) void lstm_full_v18(
    const float* __restrict__ xz,       // [B, T, 512]
    const float* __restrict__ U,        // [128, 512]
    float* __restrict__ out_last)       // [B, 128]
{
    constexpr int HN = 128;
    constexpr int GATES = 512;
    constexpr int COLS = 512;           // all 4 gates x 128 units
    constexpr int CP = COLS / 2;        // 256 col-pairs
    constexpr int NKG = 1024 / CP;      // 4 k-groups
    constexpr int KH = HN / NKG;        // 32 k per group
    constexpr int WPT = KH;             // 32 ur entries (f32 pairs)
    constexpr int KWORDS = HN;          // 128 f32 h words
    constexpr int COLSP = COLS + 2;     // 514

    __shared__ __align__(16) unsigned int hW[KWORDS];
    __shared__ __align__(16) float zpS[NKG * COLSP];

    const int tid = threadIdx.x;
    const int b = blockIdx.x;           // batch element

    const int cp = tid % CP;
    const int kq = tid / CP;            // wave-uniform (CP = 256)
    const int c0 = 2 * cp;              // local col == global gate-col
    const int wbase = kq * WPT;

    // ---- one-time: U slice into registers (2 cols x 32 k = 64 f32), PIN ----
    uint2 ur[WPT];
#pragma unroll
    for (int j = 0; j < WPT; ++j) {
        const int w = wbase + j;
        const float2 r0 = *(const float2*)(U + (size_t)w * GATES + c0);
        ur[j].x = __builtin_bit_cast(unsigned int, r0.x);
        ur[j].y = __builtin_bit_cast(unsigned int, r0.y);
    }
#pragma unroll
    for (int j = 0; j < WPT; ++j)
        asm volatile("" : "+v"(ur[j].x), "+v"(ur[j].y));

    if (tid < KWORDS) hW[tid] = 0u;     // h_0 = 0
    float cst = 0.f;

    // cell lane: thread u (< 128) owns unit u; xz cols g*128 + u
    const float* xzcell = xz + (size_t)b * T_ * GATES + tid;
    float z4[4] = {0.f, 0.f, 0.f, 0.f};
    if (tid < HN) {
#pragma unroll
        for (int g = 0; g < 4; ++g) z4[g] = xzcell[g * HN];   // t=0
    }
    __syncthreads();   // one-time init barrier

#pragma unroll 1
    for (int t = 0; t < T_; ++t) {
        // ---- phase A: dot over this thread's 32 k (U in regs, h in LDS) ----
        float acc0 = 0.f, acc1 = 0.f;
#pragma unroll
        for (int j = 0; j < WPT; j += 4) {
            const int w = wbase + j;
            const uint4 hw4 = *(const uint4*)&hW[w];    // wave-uniform broadcast
            acc0 += ubits(ur[j + 0].x) * ubits(hw4.x); acc1 += ubits(ur[j + 0].y) * ubits(hw4.x);
            acc0 += ubits(ur[j + 1].x) * ubits(hw4.y); acc1 += ubits(ur[j + 1].y) * ubits(hw4.y);
            acc0 += ubits(ur[j + 2].x) * ubits(hw4.z); acc1 += ubits(ur[j + 2].y) * ubits(hw4.z);
            acc0 += ubits(ur[j + 3].x) * ubits(hw4.w); acc1 += ubits(ur[j + 3].y) * ubits(hw4.w);
        }
        *(float2*)&zpS[kq * COLSP + c0] = make_float2(acc0, acc1);
        bar_lds();          // bar1

        // ---- phase B: cell update (threads < 128), h stays in LDS ----
        if (tid < HN) {
            float zg[4];
#pragma unroll
            for (int g = 0; g < 4; ++g) {
                float zs = z4[g];
#pragma unroll
                for (int r = 0; r < NKG; ++r) zs += zpS[r * COLSP + g * HN + tid];
                zg[g] = zs;
            }
            if (t + 1 < T_) {   // prefetch next xz
#pragma unroll
                for (int g = 0; g < 4; ++g)
                    z4[g] = xzcell[(size_t)(t + 1) * GATES + g * HN];
            }
            const float ig = fsig(zg[0]);
            const float fg = fsig(zg[1]);
            const float gg = ftanh(zg[2]);
            const float og = fsig(zg[3]);
            cst = fg * cst + ig * gg;
            const float hnew = og * ftanh(cst);

            if (t == T_ - 1) {
                out_last[(size_t)b * HN + tid] = hnew;
            } else {
                hW[tid] = __builtin_bit_cast(unsigned int, hnew);
            }
        }
        bar_lds();          // bar2 -> next dot sees h(t+1)
    }
}

// ---------------------------------------------------------------------------
// Launch
// ---------------------------------------------------------------------------
extern "C" void kernel_launch(void* const* d_in, const int* in_sizes, int n_in,
                              void* d_out, int out_size, void* d_ws, size_t ws_size,
                              hipStream_t stream)
{
    const float* x  = (const float*)d_in[0];
    const float* W0 = (const float*)d_in[1];
    const float* U0 = (const float*)d_in[2];
    const float* b0 = (const float*)d_in[3];
    const float* W1 = (const float*)d_in[4];
    const float* U1 = (const float*)d_in[5];
    const float* b1 = (const float*)d_in[6];
    const float* W2 = (const float*)d_in[7];
    const float* U2 = (const float*)d_in[8];
    const float* b2 = (const float*)d_in[9];
    const float* m0 = (const float*)d_in[10];
    const float* m1 = (const float*)d_in[11];
    const float* m2 = (const float*)d_in[12];
    float* out = (float*)d_out;

    // workspace layout:
    //   xz    : 134217728 B   (64*512*1024 floats, reused by all 3 layers)
    //   h0    :  33554432 B
    //   h1    :  33554432 B
    //   hbuf  : 2 regions x 131072 B (2 x 64 x 256 tagged words per layer)
    char* ws = (char*)d_ws;
    float* xz = (float*)ws;
    float* h0 = (float*)(ws + 134217728);
    float* h1 = (float*)(ws + 134217728 + 33554432);
    unsigned int* hb0 = (unsigned int*)(ws + 134217728 + 2 * 33554432);
    unsigned int* hb1 = hb0 + 2 * B_ * 256;

    const int M = B_ * T_;  // 32768

    // Layer 0
    gemm_mask_f16<<<dim3(1024 / 64, M / 64), 256, 0, stream>>>(x, W0, b0, m0, xz, M, 1024, 128);
    lstm_rec_v16<256, true><<<256, 1024, 0, stream>>>(xz, U0, h0, nullptr, hb0);

    // Layer 1
    gemm_mask_f16<<<dim3(1024 / 64, M / 64), 256, 0, stream>>>(h0, W1, b1, m1, xz, M, 1024, 256);
    lstm_rec_v16<256, true><<<256, 1024, 0, stream>>>(xz, U1, h1, nullptr, hb1);

    // Layer 2 (H=128): one block per batch, NO exchange, h in LDS
    gemm_mask_f16<<<dim3(512 / 64, M / 64), 256, 0, stream>>>(h1, W2, b2, m2, xz, M, 512, 256);
    lstm_full_v18<<<64, 1024, 0, stream>>>(xz, U2, out);
}

// Round 13
// 1964.353 us; speedup vs baseline: 1.3106x; 1.0774x over previous
//
#include <hip/hip_runtime.h>
#include <hip/hip_fp16.h>
#include <math.h>

#define B_ 64
#define T_ 512

typedef _Float16 h2_t __attribute__((ext_vector_type(2)));
typedef _Float16 f16x8 __attribute__((ext_vector_type(8)));
typedef float f32x4 __attribute__((ext_vector_type(4)));

__device__ __forceinline__ float fdot2u(unsigned int a, unsigned int b, float c) {
#if __has_builtin(__builtin_amdgcn_fdot2)
    return __builtin_amdgcn_fdot2(__builtin_bit_cast(h2_t, a),
                                  __builtin_bit_cast(h2_t, b), c, false);
#else
    const __half2 ah = __builtin_bit_cast(__half2, a);
    const __half2 bh = __builtin_bit_cast(__half2, b);
    const float2 af = __half22float2(ah), bf = __half22float2(bh);
    return c + af.x * bf.x + af.y * bf.y;
#endif
}
__device__ __forceinline__ unsigned int pack_h2(float x, float y) {
    const __half2 h = __float22half2_rn(make_float2(x, y));
    return __builtin_bit_cast(unsigned int, h);
}
__device__ __forceinline__ float ubits(unsigned int a) { return __builtin_bit_cast(float, a); }
__device__ __forceinline__ unsigned short f2h_bits(float x) {
    return __builtin_bit_cast(unsigned short, (_Float16)x);
}
__device__ __forceinline__ float h2f_bits(unsigned int bits) {
    return (float)__builtin_bit_cast(_Float16, (unsigned short)(bits & 0xffffu));
}

__device__ __forceinline__ float fsig(float z) { return 1.f / (1.f + __expf(-z)); }
__device__ __forceinline__ float ftanh(float z) {
    const float e = __expf(2.f * z);
    return 1.f - 2.f / (e + 1.f);
}

// LDS-only barrier: lgkmcnt(0) + s_barrier, no vmcnt drain (v12-proven).
__device__ __forceinline__ void bar_lds() {
    asm volatile("s_waitcnt lgkmcnt(0)" ::: "memory");
    __builtin_amdgcn_s_barrier();
    asm volatile("" ::: "memory");
}

// ---------------------------------------------------------------------------
// GEMM v3 (MFMA): C[M,N] = (A[M,K]*mask)@W[K,N] + bias.
// 128x128 tile, 256 threads = 4 waves (64x64 quadrant each), K-step 32,
// v_mfma_f32_16x16x32_f16. Session GEMMs ran at MfmaUtil=0 (fdot2 path,
// ~150 TF eff) vs ~67us memory floor; matmul-shaped K>=128 belongs on the
// matrix cores (G10). LDS layouts are fragment-native k-pair-packed f16:
//   AsT[m][kp], BsT[n][kp], row stride 20 u32 (80 B: 16B-aligned b128 reads,
//   <=2-way banked). Fragment mapping (lane = 16g + r):
//   A: row r, k = 8g..8g+7; B: col r, k = 8g..8g+7 (4 VGPR each);
//   C/D: col = lane&15, row = (lane>>4)*4 + reg   [m89-verified].
// ---------------------------------------------------------------------------
__global__ __launch_bounds__(256) void gemm_mask_mfma(
    const float* __restrict__ A, const float* __restrict__ W,
    const float* __restrict__ bias, const float* __restrict__ mask,
    float* __restrict__ C, int M, int N, int K)
{
    __shared__ __align__(16) unsigned int AsT[128][20];
    __shared__ __align__(16) unsigned int BsT[128][20];

    const int tid = threadIdx.x;
    const int bn = blockIdx.x;          // N/128
    const int bm = blockIdx.y;          // M/128
    const int row0 = bm * 128;
    const int col0 = bn * 128;
    const int b = row0 / T_;            // 128-row tile stays inside one batch elem

    const int wave = tid >> 6;
    const int lane = tid & 63;
    const int wm = (wave >> 1) * 64;    // wave quadrant row offset
    const int wn = (wave & 1) * 64;     // wave quadrant col offset
    const int lr = lane & 15;           // fragment row/col
    const int g  = lane >> 4;           // k-group 0..3

    f32x4 acc[4][4];
#pragma unroll
    for (int i = 0; i < 4; ++i)
#pragma unroll
        for (int j = 0; j < 4; ++j) acc[i][j] = (f32x4){0.f, 0.f, 0.f, 0.f};

    for (int kk = 0; kk < K; kk += 32) {
        // ---- stage A*mask: thread (m = tid>>1, half = tid&1 -> 16 k) ----
        {
            const int m = tid >> 1;
            const int half = tid & 1;
            const float* ap = A + (size_t)(row0 + m) * K + kk + half * 16;
            const float* mp = mask + (size_t)b * K + kk + half * 16;
            const float4 a0 = *(const float4*)(ap);
            const float4 a1 = *(const float4*)(ap + 4);
            const float4 a2 = *(const float4*)(ap + 8);
            const float4 a3 = *(const float4*)(ap + 12);
            const float4 m0 = *(const float4*)(mp);
            const float4 m1 = *(const float4*)(mp + 4);
            const float4 m2 = *(const float4*)(mp + 8);
            const float4 m3 = *(const float4*)(mp + 12);
            uint4 lo, hi;
            lo.x = pack_h2(a0.x * m0.x, a0.y * m0.y);
            lo.y = pack_h2(a0.z * m0.z, a0.w * m0.w);
            lo.z = pack_h2(a1.x * m1.x, a1.y * m1.y);
            lo.w = pack_h2(a1.z * m1.z, a1.w * m1.w);
            hi.x = pack_h2(a2.x * m2.x, a2.y * m2.y);
            hi.y = pack_h2(a2.z * m2.z, a2.w * m2.w);
            hi.z = pack_h2(a3.x * m3.x, a3.y * m3.y);
            hi.w = pack_h2(a3.z * m3.z, a3.w * m3.w);
            *(uint4*)&AsT[m][half * 8 + 0] = lo;   // 80B row stride: 16B-aligned
            *(uint4*)&AsT[m][half * 8 + 4] = hi;
        }
        // ---- stage B (W k-pair transposed): thread (kp = tid>>4, t15 = tid&15)
        // writes n = t15 + 16*i (i=0..7): LDS banks spread (20*t15 pattern).
        {
            const int kp = tid >> 4;
            const int t15 = tid & 15;
            const float* w0p = W + (size_t)(kk + 2 * kp) * N + col0 + t15;
            const float* w1p = W + (size_t)(kk + 2 * kp + 1) * N + col0 + t15;
#pragma unroll
            for (int i = 0; i < 8; ++i) {
                const int n = t15 + 16 * i;
                BsT[n][kp] = pack_h2(w0p[16 * i], w1p[16 * i]);
            }
        }
        __syncthreads();

        // ---- fragments + 16 MFMA per wave ----
        f16x8 af[4], bf[4];
#pragma unroll
        for (int i = 0; i < 4; ++i)
            af[i] = __builtin_bit_cast(f16x8, *(const uint4*)&AsT[wm + 16 * i + lr][g * 4]);
#pragma unroll
        for (int j = 0; j < 4; ++j)
            bf[j] = __builtin_bit_cast(f16x8, *(const uint4*)&BsT[wn + 16 * j + lr][g * 4]);
#pragma unroll
        for (int i = 0; i < 4; ++i)
#pragma unroll
            for (int j = 0; j < 4; ++j)
                acc[i][j] = __builtin_amdgcn_mfma_f32_16x16x32_f16(af[i], bf[j], acc[i][j], 0, 0, 0);
        __syncthreads();
    }

    // ---- epilogue: C/D mapping col = lane&15, row = (lane>>4)*4 + reg ----
#pragma unroll
    for (int j = 0; j < 4; ++j) {
        const int c = col0 + wn + 16 * j + lr;
        const float bv = bias[c];
#pragma unroll
        for (int i = 0; i < 4; ++i) {
            const int r0 = row0 + wm + 16 * i + g * 4;
            C[(size_t)(r0 + 0) * N + c] = acc[i][j][0] + bv;
            C[(size_t)(r0 + 1) * N + c] = acc[i][j][1] + bv;
            C[(size_t)(r0 + 2) * N + c] = acc[i][j][2] + bv;
            C[(size_t)(r0 + 3) * N + c] = acc[i][j][3] + bv;
        }
    }
}

// ---------------------------------------------------------------------------
// LSTM recurrence v16 (r9/r12-verified best: ~707us/dispatch): v13 2-phase
// structure + pinned-register U + conflict-free zpart. 4-way split, tagged
// L2 exchange. Lessons: (r8) INLINE phase bodies only; (r10) 2-way split
// regresses; (r11) readlane hW path regresses. UNCHANGED from r12.
// ---------------------------------------------------------------------------
template <int HN, bool F16>
__global__ __launch_bounds__(1024, 4) void lstm_rec_v16(
    const float* __restrict__ xz,       // [B, T, 4*HN]
    const float* __restrict__ U,        // [HN, 4*HN]
    float* __restrict__ hout,           // [B, T, HN] or nullptr
    float* __restrict__ out_last,       // [B, HN] or nullptr
    unsigned int* __restrict__ hbuf)    // [2][B_*HN] tagged words
{
    constexpr int GATES = 4 * HN;
    constexpr int COLS = HN;
    constexpr int CP = COLS / 2;
    constexpr int NKG = 1024 / CP;
    constexpr int KH = HN / NKG;
    constexpr int HB = HN / 4;
    constexpr int KWORDS = F16 ? HN / 2 : HN;
    constexpr int WPT = F16 ? KH / 2 : KH;
    constexpr int COLSP = COLS + 2;
    constexpr int NR = 3 * HB / 2;

    __shared__ __align__(16) unsigned int hW[KWORDS];
    __shared__ __align__(16) float zpS[NKG * COLSP];

    const int tid = threadIdx.x;
    const int q = blockIdx.x >> 6;      // quarter 0..3
    const int b = blockIdx.x & 63;      // batch element (siblings 64 apart -> same XCD)

    const int cp = tid % CP;
    const int kq = tid / CP;            // wave-uniform (CP % 64 == 0)
    const int c0 = 2 * cp;
    const int group = c0 / HB;
    const int gcol = group * HN + q * HB + (c0 % HB);
    const int wbase = kq * WPT;

    // ---- one-time: load this thread's U slice into REGISTERS, then PIN ----
    uint2 ur[WPT];
#pragma unroll
    for (int j = 0; j < WPT; ++j) {
        const int w = wbase + j;
        if constexpr (F16) {
            const float2 r0 = *(const float2*)(U + (size_t)(2 * w) * GATES + gcol);
            const float2 r1 = *(const float2*)(U + (size_t)(2 * w + 1) * GATES + gcol);
            ur[j].x = pack_h2(r0.x, r1.x);
            ur[j].y = pack_h2(r0.y, r1.y);
        } else {
            const float2 r0 = *(const float2*)(U + (size_t)w * GATES + gcol);
            ur[j].x = __builtin_bit_cast(unsigned int, r0.x);
            ur[j].y = __builtin_bit_cast(unsigned int, r0.y);
        }
    }
#pragma unroll
    for (int j = 0; j < WPT; ++j)
        asm volatile("" : "+v"(ur[j].x), "+v"(ur[j].y));

    if (tid < KWORDS) hW[tid] = 0u;     // h_0 = 0
    float cst = 0.f;

    const float* xzcell = xz + (size_t)b * T_ * GATES + q * HB + tid;
    float z4[4] = {0.f, 0.f, 0.f, 0.f};
    if (tid < HB) {
#pragma unroll
        for (int g = 0; g < 4; ++g) z4[g] = xzcell[(size_t)g * HN];   // t=0
    }
    __syncthreads();   // one-time init barrier

#pragma unroll 1
    for (int t = 0; t < T_; ++t) {
        // ---- phase A: dot (U in regs, h from LDS) ----
        float acc0 = 0.f, acc1 = 0.f;
#pragma unroll
        for (int j = 0; j < WPT; j += 4) {
            const int w = wbase + j;
            const uint4 hw4 = *(const uint4*)&hW[w];    // wave-uniform broadcast
            if constexpr (F16) {
                acc0 = fdot2u(ur[j + 0].x, hw4.x, acc0); acc1 = fdot2u(ur[j + 0].y, hw4.x, acc1);
                acc0 = fdot2u(ur[j + 1].x, hw4.y, acc0); acc1 = fdot2u(ur[j + 1].y, hw4.y, acc1);
                acc0 = fdot2u(ur[j + 2].x, hw4.z, acc0); acc1 = fdot2u(ur[j + 2].y, hw4.z, acc1);
                acc0 = fdot2u(ur[j + 3].x, hw4.w, acc0); acc1 = fdot2u(ur[j + 3].y, hw4.w, acc1);
            } else {
                acc0 += ubits(ur[j + 0].x) * ubits(hw4.x); acc1 += ubits(ur[j + 0].y) * ubits(hw4.x);
                acc0 += ubits(ur[j + 1].x) * ubits(hw4.y); acc1 += ubits(ur[j + 1].y) * ubits(hw4.y);
                acc0 += ubits(ur[j + 2].x) * ubits(hw4.z); acc1 += ubits(ur[j + 2].y) * ubits(hw4.z);
                acc0 += ubits(ur[j + 3].x) * ubits(hw4.w); acc1 += ubits(ur[j + 3].y) * ubits(hw4.w);
            }
        }
        *(float2*)&zpS[kq * COLSP + c0] = make_float2(acc0, acc1);
        bar_lds();          // bar1

        const unsigned int tag = (unsigned int)(t + 1);
        unsigned int* hslot = hbuf + (size_t)(t & 1) * B_ * HN + b * HN;

        if (tid < HB) {
            float zg[4];
#pragma unroll
            for (int g = 0; g < 4; ++g) {
                float zs = z4[g];
#pragma unroll
                for (int r = 0; r < NKG; ++r) zs += zpS[r * COLSP + g * HB + tid];
                zg[g] = zs;
            }
            if (t + 1 < T_) {
#pragma unroll
                for (int g = 0; g < 4; ++g)
                    z4[g] = xzcell[(size_t)(t + 1) * GATES + (size_t)g * HN];
            }
            const float ig = fsig(zg[0]);
            const float fg = fsig(zg[1]);
            const float gg = ftanh(zg[2]);
            const float og = fsig(zg[3]);
            cst = fg * cst + ig * gg;
            const float hnew = og * ftanh(cst);

            if (hout) hout[((size_t)b * T_ + t) * HN + q * HB + tid] = hnew;
            if (t == T_ - 1) {
                if (out_last) out_last[(size_t)b * HN + q * HB + tid] = hnew;
            } else {
                const unsigned short h16 = f2h_bits(hnew);
                __hip_atomic_store(&hslot[q * HB + tid],
                                   ((unsigned int)tag << 16) | (unsigned int)h16,
                                   __ATOMIC_RELAXED, __HIP_MEMORY_SCOPE_AGENT);
                if constexpr (F16) {
                    reinterpret_cast<unsigned short*>(hW)[q * HB + tid] = h16;
                } else {
                    hW[q * HB + tid] = __builtin_bit_cast(unsigned int, hnew);
                }
            }
        } else if (tid >= 64 && tid < 64 + NR && t < T_ - 1) {
            const int idx = tid - 64;
            const int qp0 = q * (HB / 2);
            const int p = idx + (idx >= qp0 ? (HB / 2) : 0);   // remote pair index
            const unsigned long long* hq = (const unsigned long long*)hslot;
            unsigned long long v = __hip_atomic_load(&hq[p],
                __ATOMIC_RELAXED, __HIP_MEMORY_SCOPE_AGENT);
            while (((v >> 16) & 0xffffu) != tag || (v >> 48) != tag)
                v = __hip_atomic_load(&hq[p],
                    __ATOMIC_RELAXED, __HIP_MEMORY_SCOPE_AGENT);
            if constexpr (F16) {
                hW[p] = (unsigned int)(v & 0xffffu) |
                        ((unsigned int)((v >> 32) & 0xffffu) << 16);
            } else {
                hW[2 * p + 0] = __builtin_bit_cast(unsigned int, h2f_bits((unsigned int)v));
                hW[2 * p + 1] = __builtin_bit_cast(unsigned int, h2f_bits((unsigned int)(v >> 32)));
            }
        }
        bar_lds();          // bar2
    }
}

// ---------------------------------------------------------------------------
// LSTM recurrence v18-full (r9/r12-verified: ~470us): ONE block per batch
// element, NO exchange, h entirely in LDS. UNCHANGED from r12.
// ---------------------------------------------------------------------------
__global__ __launch_bounds__(1024, 4) void lstm_full_v18(
    const float* __restrict__ xz,       // [B, T, 512]
    const float* __restrict__ U,        // [128, 512]
    float* __restrict__ out_last)       // [B, 128]
{
    constexpr int HN = 128;
    constexpr int GATES = 512;
    constexpr int COLS = 512;           // all 4 gates x 128 units
    constexpr int CP = COLS / 2;        // 256 col-pairs
    constexpr int NKG = 1024 / CP;      // 4 k-groups
    constexpr int KH = HN / NKG;        // 32 k per group
    constexpr int WPT = KH;             // 32 ur entries (f32 pairs)
    constexpr int KWORDS = HN;          // 128 f32 h words
    constexpr int COLSP = COLS + 2;     // 514

    __shared__ __align__(16) unsigned int hW[KWORDS];
    __shared__ __align__(16) float zpS[NKG * COLSP];

    const int tid = threadIdx.x;
    const int b = blockIdx.x;           // batch element

    const int cp = tid % CP;
    const int kq = tid / CP;            // wave-uniform (CP = 256)
    const int c0 = 2 * cp;              // local col == global gate-col
    const int wbase = kq * WPT;

    // ---- one-time: U slice into registers (2 cols x 32 k = 64 f32), PIN ----
    uint2 ur[WPT];
#pragma unroll
    for (int j = 0; j < WPT; ++j) {
        const int w = wbase + j;
        const float2 r0 = *(const float2*)(U + (size_t)w * GATES + c0);
        ur[j].x = __builtin_bit_cast(unsigned int, r0.x);
        ur[j].y = __builtin_bit_cast(unsigned int, r0.y);
    }
#pragma unroll
    for (int j = 0; j < WPT; ++j)
        asm volatile("" : "+v"(ur[j].x), "+v"(ur[j].y));

    if (tid < KWORDS) hW[tid] = 0u;     // h_0 = 0
    float cst = 0.f;

    // cell lane: thread u (< 128) owns unit u; xz cols g*128 + u
    const float* xzcell = xz + (size_t)b * T_ * GATES + tid;
    float z4[4] = {0.f, 0.f, 0.f, 0.f};
    if (tid < HN) {
#pragma unroll
        for (int g = 0; g < 4; ++g) z4[g] = xzcell[g * HN];   // t=0
    }
    __syncthreads();   // one-time init barrier

#pragma unroll 1
    for (int t = 0; t < T_; ++t) {
        // ---- phase A: dot over this thread's 32 k (U in regs, h in LDS) ----
        float acc0 = 0.f, acc1 = 0.f;
#pragma unroll
        for (int j = 0; j < WPT; j += 4) {
            const int w = wbase + j;
            const uint4 hw4 = *(const uint4*)&hW[w];    // wave-uniform broadcast
            acc0 += ubits(ur[j + 0].x) * ubits(hw4.x); acc1 += ubits(ur[j + 0].y) * ubits(hw4.x);
            acc0 += ubits(ur[j + 1].x) * ubits(hw4.y); acc1 += ubits(ur[j + 1].y) * ubits(hw4.y);
            acc0 += ubits(ur[j + 2].x) * ubits(hw4.z); acc1 += ubits(ur[j + 2].y) * ubits(hw4.z);
            acc0 += ubits(ur[j + 3].x) * ubits(hw4.w); acc1 += ubits(ur[j + 3].y) * ubits(hw4.w);
        }
        *(float2*)&zpS[kq * COLSP + c0] = make_float2(acc0, acc1);
        bar_lds();          // bar1

        // ---- phase B: cell update (threads < 128), h stays in LDS ----
        if (tid < HN) {
            float zg[4];
#pragma unroll
            for (int g = 0; g < 4; ++g) {
                float zs = z4[g];
#pragma unroll
                for (int r = 0; r < NKG; ++r) zs += zpS[r * COLSP + g * HN + tid];
                zg[g] = zs;
            }
            if (t + 1 < T_) {   // prefetch next xz
#pragma unroll
                for (int g = 0; g < 4; ++g)
                    z4[g] = xzcell[(size_t)(t + 1) * GATES + g * HN];
            }
            const float ig = fsig(zg[0]);
            const float fg = fsig(zg[1]);
            const float gg = ftanh(zg[2]);
            const float og = fsig(zg[3]);
            cst = fg * cst + ig * gg;
            const float hnew = og * ftanh(cst);

            if (t == T_ - 1) {
                out_last[(size_t)b * HN + tid] = hnew;
            } else {
                hW[tid] = __builtin_bit_cast(unsigned int, hnew);
            }
        }
        bar_lds();          // bar2 -> next dot sees h(t+1)
    }
}

// ---------------------------------------------------------------------------
// Launch
// ---------------------------------------------------------------------------
extern "C" void kernel_launch(void* const* d_in, const int* in_sizes, int n_in,
                              void* d_out, int out_size, void* d_ws, size_t ws_size,
                              hipStream_t stream)
{
    const float* x  = (const float*)d_in[0];
    const float* W0 = (const float*)d_in[1];
    const float* U0 = (const float*)d_in[2];
    const float* b0 = (const float*)d_in[3];
    const float* W1 = (const float*)d_in[4];
    const float* U1 = (const float*)d_in[5];
    const float* b1 = (const float*)d_in[6];
    const float* W2 = (const float*)d_in[7];
    const float* U2 = (const float*)d_in[8];
    const float* b2 = (const float*)d_in[9];
    const float* m0 = (const float*)d_in[10];
    const float* m1 = (const float*)d_in[11];
    const float* m2 = (const float*)d_in[12];
    float* out = (float*)d_out;

    // workspace layout:
    //   xz    : 134217728 B   (64*512*1024 floats, reused by all 3 layers)
    //   h0    :  33554432 B
    //   h1    :  33554432 B
    //   hbuf  : 2 regions x 131072 B (2 x 64 x 256 tagged words per layer)
    char* ws = (char*)d_ws;
    float* xz = (float*)ws;
    float* h0 = (float*)(ws + 134217728);
    float* h1 = (float*)(ws + 134217728 + 33554432);
    unsigned int* hb0 = (unsigned int*)(ws + 134217728 + 2 * 33554432);
    unsigned int* hb1 = hb0 + 2 * B_ * 256;

    const int M = B_ * T_;  // 32768

    // Layer 0
    gemm_mask_mfma<<<dim3(1024 / 128, M / 128), 256, 0, stream>>>(x, W0, b0, m0, xz, M, 1024, 128);
    lstm_rec_v16<256, true><<<256, 1024, 0, stream>>>(xz, U0, h0, nullptr, hb0);

    // Layer 1
    gemm_mask_mfma<<<dim3(1024 / 128, M / 128), 256, 0, stream>>>(h0, W1, b1, m1, xz, M, 1024, 256);
    lstm_rec_v16<256, true><<<256, 1024, 0, stream>>>(xz, U1, h1, nullptr, hb1);

    // Layer 2 (H=128): one block per batch, NO exchange, h in LDS
    gemm_mask_mfma<<<dim3(512 / 128, M / 128), 256, 0, stream>>>(h1, W2, b2, m2, xz, M, 512, 256);
    lstm_full_v18<<<64, 1024, 0, stream>>>(xz, U2, out);
}